// Round 3
// baseline (649.319 us; speedup 1.0000x reference)
//
#include <hip/hip_runtime.h>
#include <stdint.h>

#define S_LEN 2048
#define BATCH 2
#define NH 32
#define NKV 8
#define HD 128
#define NE 6144   // extracted columns of zxbcdt: x(1024) | B(1024) | C(4096)

typedef __attribute__((ext_vector_type(8))) short short8;
typedef __attribute__((ext_vector_type(4))) float floatx4;

__device__ __forceinline__ unsigned short f2bf(float f) {
    union { float f; uint32_t u; } v; v.f = f;
    uint32_t u = v.u;
    u += 0x7FFFu + ((u >> 16) & 1u);   // RTN-even (inputs are finite)
    return (unsigned short)(u >> 16);
}
__device__ __forceinline__ float bf2f(unsigned short h) {
    union { uint32_t u; float f; } v; v.u = ((uint32_t)h) << 16;
    return v.f;
}
__device__ __forceinline__ uint32_t rtn_u(float f) {
    union { float f; uint32_t u; } v; v.f = f;
    return v.u + 0x7FFFu + ((v.u >> 16) & 1u);
}
// pack two fp32 -> {bf16(a) lo, bf16(b) hi} in one v_perm after rounding
__device__ __forceinline__ uint32_t pack_bf2(float a, float b) {
    return __builtin_amdgcn_perm(rtn_u(b), rtn_u(a), 0x07060302);
}

// ---------------- cast fp32 -> bf16, 4 elems/thread ----------------
__global__ void cast_f32_bf16(const float* __restrict__ in,
                              unsigned short* __restrict__ out, int n4) {
    int i = blockIdx.x * blockDim.x + threadIdx.x;
    if (i >= n4) return;
    float4 f = reinterpret_cast<const float4*>(in)[i];
    ushort4 o;
    o.x = f2bf(f.x); o.y = f2bf(f.y); o.z = f2bf(f.z); o.w = f2bf(f.w);
    reinterpret_cast<ushort4*>(out)[i] = o;
}

// ---------------- m97-style B^T GEMM: C[M,N] = A[M,K] * Bt[N,K]^T ----------------
template <int OUT_BF16>
__global__ void __launch_bounds__(256)
gemm_bt(const unsigned short* __restrict__ A, const unsigned short* __restrict__ Bt,
        void* __restrict__ Cv, int M, int N, int K) {
    __shared__ unsigned short As[128 * 32];
    __shared__ unsigned short Bs[128 * 32];
    const int tid  = threadIdx.x;
    const int w    = tid >> 6;
    const int lane = tid & 63;
    const int quad = lane >> 4;
    const int l16  = lane & 15;
    const int wm   = w >> 1, wn = w & 1;
    const int m0 = blockIdx.y * 128, n0 = blockIdx.x * 128;

    floatx4 acc[4][4];
#pragma unroll
    for (int i = 0; i < 4; i++)
#pragma unroll
        for (int j = 0; j < 4; j++) acc[i][j] = {0.f, 0.f, 0.f, 0.f};

    const int lr = lane >> 2;        // row within 16-row chunk
    const int lk = (lane & 3) * 8;   // k-elem offset within 32
    const int KT = K >> 5;

    for (int kt = 0; kt < KT; ++kt) {
        const int k0 = kt << 5;
        __syncthreads();
#pragma unroll
        for (int c = 0; c < 2; ++c) {
            const int chunk = w * 2 + c;  // wave-uniform
            const unsigned short* ga = A  + (size_t)(m0 + chunk * 16 + lr) * K + k0 + lk;
            __builtin_amdgcn_global_load_lds(
                (const __attribute__((address_space(1))) void*)ga,
                (__attribute__((address_space(3))) void*)(As + chunk * 512), 16, 0, 0);
            const unsigned short* gb = Bt + (size_t)(n0 + chunk * 16 + lr) * K + k0 + lk;
            __builtin_amdgcn_global_load_lds(
                (const __attribute__((address_space(1))) void*)gb,
                (__attribute__((address_space(3))) void*)(Bs + chunk * 512), 16, 0, 0);
        }
        __syncthreads();
        short8 af[4], bf[4];
#pragma unroll
        for (int t = 0; t < 4; ++t) {
            af[t] = *reinterpret_cast<const short8*>(As + (wm * 64 + t * 16 + l16) * 32 + quad * 8);
            bf[t] = *reinterpret_cast<const short8*>(Bs + (wn * 64 + t * 16 + l16) * 32 + quad * 8);
        }
#pragma unroll
        for (int i = 0; i < 4; i++)
#pragma unroll
            for (int j = 0; j < 4; j++)
                acc[i][j] = __builtin_amdgcn_mfma_f32_16x16x32_bf16(af[i], bf[j], acc[i][j], 0, 0, 0);
    }

#pragma unroll
    for (int i = 0; i < 4; i++)
#pragma unroll
        for (int j = 0; j < 4; j++) {
            const int row = m0 + wm * 64 + i * 16 + quad * 4;
            const int col = n0 + wn * 64 + j * 16 + l16;
#pragma unroll
            for (int r = 0; r < 4; r++) {
                float vv = acc[i][j][r];
                if (OUT_BF16)
                    ((unsigned short*)Cv)[(size_t)(row + r) * N + col] = f2bf(vv);
                else
                    ((float*)Cv)[(size_t)(row + r) * N + col] = vv;
            }
        }
}

// ---------------- RoPE + split/reshape ----------------
// Z: [4096 tokens][6144] bf16. Q[B,NH,S,HD] (pre-scaled by log2e/sqrt(128)),
// K[B,NKV,S,HD], Vt[B,NKV,HD,S].
#define QSCALE 0.12748539509360f   // log2(e) / sqrt(128)
__global__ void rope_split(const unsigned short* __restrict__ Z,
                           unsigned short* __restrict__ Q,
                           unsigned short* __restrict__ Kb,
                           unsigned short* __restrict__ Vt) {
    const int PER_TOK = 2048 + 512 + 1024;  // q-pairs + k-pairs + v-elems
    int idx = blockIdx.x * blockDim.x + threadIdx.x;
    if (idx >= BATCH * S_LEN * PER_TOK) return;
    int t = idx / PER_TOK;
    int r = idx - t * PER_TOK;
    int b = t / S_LEN, s = t - b * S_LEN;
    const unsigned short* z = Z + (size_t)t * NE;
    if (r < 2048) {                 // q pair: C section
        int h = r >> 6, j = r & 63;
        float x0 = bf2f(z[2048 + h * 128 + j]);
        float x1 = bf2f(z[2048 + h * 128 + j + 64]);
        float inv = exp2f((float)j * -0.20762050593f);   // 10000^(-j/64)
        float c, sn; sincosf((float)s * inv, &sn, &c);
        size_t base = ((size_t)(b * NH + h) * S_LEN + s) * HD;
        Q[base + j]      = f2bf((x0 * c - x1 * sn) * QSCALE);
        Q[base + j + 64] = f2bf((x1 * c + x0 * sn) * QSCALE);
    } else if (r < 2560) {          // k pair: B section
        int rr = r - 2048; int kh = rr >> 6, j = rr & 63;
        float x0 = bf2f(z[1024 + kh * 128 + j]);
        float x1 = bf2f(z[1024 + kh * 128 + j + 64]);
        float inv = exp2f((float)j * -0.20762050593f);
        float c, sn; sincosf((float)s * inv, &sn, &c);
        size_t base = ((size_t)(b * NKV + kh) * S_LEN + s) * HD;
        Kb[base + j]      = f2bf(x0 * c - x1 * sn);
        Kb[base + j + 64] = f2bf(x1 * c + x0 * sn);
    } else {                        // v elem: x section, transposed store
        int m = r - 2560; int kh = m >> 7, d = m & 127;
        Vt[((size_t)(b * NKV + kh) * HD + d) * S_LEN + s] = z[m];
    }
}

// ---------------- Flash attention v3 (causal, GQA 4:1) ----------------
// Block = 4 waves x 32 q-rows = 128 q. kv tiles of 64.
// K staged in LDS (global_load_lds w16, chunk^(row&7) swizzle); V read direct
// from global (B-frag b128, full-line across kappa loop); Q register-resident.
// S^T orientation (A=K, B=Q): lane holds 4 consecutive kv per q-row ->
// packed b64 P-writes; lsum = 2 scalars/lane, one end reduction.
// exp2-no-max (Q pre-scaled to log2 domain) — validated in round 2.
__global__ void __launch_bounds__(256)
attn_kernel(const unsigned short* __restrict__ Q,
            const unsigned short* __restrict__ Kb,
            const unsigned short* __restrict__ Vt,
            unsigned short* __restrict__ Ob) {
    __shared__ unsigned short Ks[64 * 128];   // [kv 64][d 128], 16B-chunk swizzle, 16 KB
    __shared__ unsigned short Ps[4][32 * 64]; // per-wave [q 32][kv 64], 8B-slot swizzle, 16 KB
    const int tid  = threadIdx.x;
    const int w    = tid >> 6;
    const int lane = tid & 63;
    const int quad = lane >> 4;
    const int l16  = lane & 15;
    const int blk = blockIdx.x;
    const int qt = 15 - (blk >> 6);      // heavy q-tiles dispatch first
    const int bh = blk & 63;
    const int h = bh & 31, b = bh >> 5;
    const int kvh = h >> 2;
    const int q0blk = qt * 128;
    const int wq0 = q0blk + w * 32;

    const unsigned short* Qbase = Q  + ((size_t)(b * NH  + h)   * S_LEN) * HD;
    const unsigned short* Kbase = Kb + ((size_t)(b * NKV + kvh) * S_LEN) * HD;
    const unsigned short* Vbase = Vt + ((size_t)(b * NKV + kvh) * HD) * S_LEN;

    // Q B-frags: qf[q_t][ks]: n=l16 -> q=wq0+q_t*16+l16 ; k=quad*8+j -> d=ks*32+quad*8+j
    short8 qf[2][4];
#pragma unroll
    for (int q_t = 0; q_t < 2; ++q_t) {
        const unsigned short* qrow = Qbase + (size_t)(wq0 + q_t * 16 + l16) * HD + quad * 8;
#pragma unroll
        for (int ks = 0; ks < 4; ++ks)
            qf[q_t][ks] = *reinterpret_cast<const short8*>(qrow + ks * 32);
    }

    floatx4 oacc[2][8];
#pragma unroll
    for (int q_t = 0; q_t < 2; ++q_t)
#pragma unroll
        for (int dt = 0; dt < 8; ++dt) oacc[q_t][dt] = {0.f, 0.f, 0.f, 0.f};
    float lsum[2] = {0.f, 0.f};

    const int stg_row = lane >> 4;       // row-in-4 group for K staging
    const int stg_pc  = lane & 15;
    unsigned short* pw = &Ps[w][0];
    const int e2 = (l16 & 7) << 1;       // P-buffer XOR swizzle (parity-preserving)
    const int kv_end = q0blk + 128;

    for (int kv0 = 0; kv0 < kv_end; kv0 += 64) {
        __syncthreads();   // previous-iter Ks reads complete before overwrite
        // ---- stage K tile (64 rows x 256 B): 16 instrs, 4 per wave ----
#pragma unroll
        for (int c = 0; c < 4; ++c) {
            const int bI = w * 4 + c;                   // wave-uniform
            const int row = bI * 4 + stg_row;           // 0..63
            const int lc = stg_pc ^ (row & 7);
            const unsigned short* ga = Kbase + (size_t)(kv0 + row) * HD + lc * 8;
            __builtin_amdgcn_global_load_lds(
                (const __attribute__((address_space(1))) void*)ga,
                (__attribute__((address_space(3))) void*)(Ks + bI * 512), 16, 0, 0);
        }
        __syncthreads();   // staging complete

        if (kv0 < wq0 + 32) {            // wave has at least one unmasked column
            const bool diag = (kv0 + 63 > wq0);
            // ---- QK^T (S^T): A=K (m=kv, 4 tiles), B=Q (n=q, 2 tiles), 4 k-chunks ----
            floatx4 sacc[2][4];
#pragma unroll
            for (int q_t = 0; q_t < 2; ++q_t)
#pragma unroll
                for (int mt = 0; mt < 4; ++mt) sacc[q_t][mt] = {0.f, 0.f, 0.f, 0.f};
#pragma unroll
            for (int ks = 0; ks < 4; ++ks) {
#pragma unroll
                for (int mt = 0; mt < 4; ++mt) {
                    const int row = mt * 16 + l16;
                    const int slot = (ks * 4 + quad) ^ (l16 & 7);
                    short8 kf = *reinterpret_cast<const short8*>(Ks + row * 128 + slot * 8);
#pragma unroll
                    for (int q_t = 0; q_t < 2; ++q_t)
                        sacc[q_t][mt] = __builtin_amdgcn_mfma_f32_16x16x32_bf16(
                            kf, qf[q_t][ks], sacc[q_t][mt], 0, 0, 0);
                }
            }
            // ---- exp2 + mask + packed P store ----
#pragma unroll
            for (int q_t = 0; q_t < 2; ++q_t) {
                const int qrow = wq0 + q_t * 16 + l16;
                const int prow = q_t * 16 + l16;
#pragma unroll
                for (int mt = 0; mt < 4; ++mt) {
                    const int kvb = kv0 + mt * 16 + quad * 4;
                    float p0 = exp2f(sacc[q_t][mt][0]);
                    float p1 = exp2f(sacc[q_t][mt][1]);
                    float p2 = exp2f(sacc[q_t][mt][2]);
                    float p3 = exp2f(sacc[q_t][mt][3]);
                    if (diag) {
                        p0 = (kvb + 0 <= qrow) ? p0 : 0.f;
                        p1 = (kvb + 1 <= qrow) ? p1 : 0.f;
                        p2 = (kvb + 2 <= qrow) ? p2 : 0.f;
                        p3 = (kvb + 3 <= qrow) ? p3 : 0.f;
                    }
                    lsum[q_t] += (p0 + p1) + (p2 + p3);
                    const int phys = (mt * 4 + quad) ^ e2;   // 8B slot, parity kept
                    uint2 pk; pk.x = pack_bf2(p0, p1); pk.y = pack_bf2(p2, p3);
                    *reinterpret_cast<uint2*>(pw + prow * 64 + phys * 4) = pk;
                }
            }
            // ---- PV: A=P (LDS, wave-private), B=V^T (direct global b128) ----
#pragma unroll
            for (int kp = 0; kp < 2; ++kp) {
                short8 pf[2];
#pragma unroll
                for (int q_t = 0; q_t < 2; ++q_t) {
                    const int phys = (kp * 8 + quad * 2) ^ e2;
                    pf[q_t] = *reinterpret_cast<const short8*>(
                        pw + (q_t * 16 + l16) * 64 + phys * 4);
                }
                const unsigned short* vp = Vbase + (size_t)l16 * S_LEN + kv0 + kp * 32 + quad * 8;
#pragma unroll
                for (int dt = 0; dt < 8; ++dt) {
                    short8 vf = *reinterpret_cast<const short8*>(vp + (size_t)dt * 16 * S_LEN);
#pragma unroll
                    for (int q_t = 0; q_t < 2; ++q_t)
                        oacc[q_t][dt] = __builtin_amdgcn_mfma_f32_16x16x32_bf16(
                            pf[q_t], vf, oacc[q_t][dt], 0, 0, 0);
                }
            }
        }
    }

    // ---- final row-sum reduce + write ----
#pragma unroll
    for (int q_t = 0; q_t < 2; ++q_t) {
        float s = lsum[q_t];
        s += __shfl_xor(s, 16);
        s += __shfl_xor(s, 32);
        float linv = 1.0f / s;           // lane (any quad, l16) holds sum for q=q_t*16+l16
#pragma unroll
        for (int r = 0; r < 4; ++r) {
            const float lr = __shfl(linv, quad * 4 + r);   // sum for q-row quad*4+r
            const int row = wq0 + q_t * 16 + quad * 4 + r;
#pragma unroll
            for (int dt = 0; dt < 8; ++dt) {
                const int d = dt * 16 + l16;
                Ob[((size_t)(b * S_LEN + row)) * 4096 + h * 128 + d] =
                    f2bf(oacc[q_t][dt][r] * lr);
            }
        }
    }
}

extern "C" void kernel_launch(void* const* d_in, const int* in_sizes, int n_in,
                              void* d_out, int out_size, void* d_ws, size_t ws_size,
                              hipStream_t stream) {
    const float* u     = (const float*)d_in[0];
    const float* W_in  = (const float*)d_in[1];
    const float* W_out = (const float*)d_in[2];
    float* out = (float*)d_out;

    char* ws = (char*)d_ws;
    unsigned short* u_bf    = (unsigned short*)(ws);                    //  16,777,216 B
    unsigned short* win_bf  = (unsigned short*)(ws + 16777216);         //  25,165,824 B
    unsigned short* wout_bf = (unsigned short*)(ws + 41943040);         //  16,777,216 B
    unsigned short* Z       = (unsigned short*)(ws + 58720256);         //  50,331,648 B
    unsigned short* Qb      = (unsigned short*)(ws + 109051904);        //  33,554,432 B
    unsigned short* Kv      = (unsigned short*)(ws + 142606336);        //   8,388,608 B
    unsigned short* Vt      = (unsigned short*)(ws + 150994944);        //   8,388,608 B
    unsigned short* Ob      = (unsigned short*)(ws + 159383552);        //  33,554,432 B
    // total: 192,937,984 B

    {   // casts
        int n4 = (2 * 2048 * 2048) / 4;
        cast_f32_bf16<<<(n4 + 255) / 256, 256, 0, stream>>>(u, u_bf, n4);
        n4 = (6144 * 2048) / 4;   // only the used rows [4096,10240) of W_in
        cast_f32_bf16<<<(n4 + 255) / 256, 256, 0, stream>>>(W_in + (size_t)4096 * 2048, win_bf, n4);
        n4 = (2048 * 4096) / 4;
        cast_f32_bf16<<<(n4 + 255) / 256, 256, 0, stream>>>(W_out, wout_bf, n4);
    }
    {   // GEMM1: Z[4096,6144] = u_bf[4096,2048] @ win_bf[6144,2048]^T
        dim3 g(6144 / 128, 4096 / 128);
        gemm_bt<1><<<g, 256, 0, stream>>>(u_bf, win_bf, Z, 4096, 6144, 2048);
    }
    {   // RoPE + split
        int n = BATCH * S_LEN * 3584;
        rope_split<<<(n + 255) / 256, 256, 0, stream>>>(Z, Qb, Kv, Vt);
    }
    // attention: grid = (S/128) * B * NH, heavy q-tiles first
    attn_kernel<<<BATCH * NH * (S_LEN / 128), 256, 0, stream>>>(Qb, Kv, Vt, Ob);
    {   // GEMM2: out[4096,2048] = Ob[4096,4096] @ wout_bf[2048,4096]^T  (fp32 store)
        dim3 g(2048 / 128, 4096 / 128);
        gemm_bt<0><<<g, 256, 0, stream>>>(Ob, wout_bf, out, 4096, 2048, 4096);
    }
}

// Round 4
// 616.221 us; speedup vs baseline: 1.0537x; 1.0537x over previous
//
#include <hip/hip_runtime.h>
#include <stdint.h>

#define S_LEN 2048
#define BATCH 2
#define NH 32
#define NKV 8
#define HD 128
#define NE 6144   // extracted columns of zxbcdt: x(1024) | B(1024) | C(4096)

typedef __attribute__((ext_vector_type(8))) short short8;
typedef __attribute__((ext_vector_type(4))) float floatx4;

__device__ __forceinline__ unsigned short f2bf(float f) {
    union { float f; uint32_t u; } v; v.f = f;
    uint32_t u = v.u;
    u += 0x7FFFu + ((u >> 16) & 1u);   // RTN-even (inputs are finite)
    return (unsigned short)(u >> 16);
}
__device__ __forceinline__ float bf2f(unsigned short h) {
    union { uint32_t u; float f; } v; v.u = ((uint32_t)h) << 16;
    return v.f;
}
__device__ __forceinline__ uint32_t rtn_u(float f) {
    union { float f; uint32_t u; } v; v.f = f;
    return v.u + 0x7FFFu + ((v.u >> 16) & 1u);
}
// pack two fp32 -> {bf16(a) lo, bf16(b) hi} in one v_perm after rounding
__device__ __forceinline__ uint32_t pack_bf2(float a, float b) {
    return __builtin_amdgcn_perm(rtn_u(b), rtn_u(a), 0x07060302);
}

// ---------------- cast fp32 -> bf16, 4 elems/thread ----------------
__global__ void cast_f32_bf16(const float* __restrict__ in,
                              unsigned short* __restrict__ out, int n4) {
    int i = blockIdx.x * blockDim.x + threadIdx.x;
    if (i >= n4) return;
    float4 f = reinterpret_cast<const float4*>(in)[i];
    ushort4 o;
    o.x = f2bf(f.x); o.y = f2bf(f.y); o.z = f2bf(f.z); o.w = f2bf(f.w);
    reinterpret_cast<ushort4*>(out)[i] = o;
}

// ---------------- m97-style B^T GEMM: C[M,N] = A[M,K] * Bt[N,K]^T ----------------
template <int OUT_BF16>
__global__ void __launch_bounds__(256)
gemm_bt(const unsigned short* __restrict__ A, const unsigned short* __restrict__ Bt,
        void* __restrict__ Cv, int M, int N, int K) {
    __shared__ unsigned short As[128 * 32];
    __shared__ unsigned short Bs[128 * 32];
    const int tid  = threadIdx.x;
    const int w    = tid >> 6;
    const int lane = tid & 63;
    const int quad = lane >> 4;
    const int l16  = lane & 15;
    const int wm   = w >> 1, wn = w & 1;
    const int m0 = blockIdx.y * 128, n0 = blockIdx.x * 128;

    floatx4 acc[4][4];
#pragma unroll
    for (int i = 0; i < 4; i++)
#pragma unroll
        for (int j = 0; j < 4; j++) acc[i][j] = {0.f, 0.f, 0.f, 0.f};

    const int lr = lane >> 2;        // row within 16-row chunk
    const int lk = (lane & 3) * 8;   // k-elem offset within 32
    const int KT = K >> 5;

    for (int kt = 0; kt < KT; ++kt) {
        const int k0 = kt << 5;
        __syncthreads();
#pragma unroll
        for (int c = 0; c < 2; ++c) {
            const int chunk = w * 2 + c;  // wave-uniform
            const unsigned short* ga = A  + (size_t)(m0 + chunk * 16 + lr) * K + k0 + lk;
            __builtin_amdgcn_global_load_lds(
                (const __attribute__((address_space(1))) void*)ga,
                (__attribute__((address_space(3))) void*)(As + chunk * 512), 16, 0, 0);
            const unsigned short* gb = Bt + (size_t)(n0 + chunk * 16 + lr) * K + k0 + lk;
            __builtin_amdgcn_global_load_lds(
                (const __attribute__((address_space(1))) void*)gb,
                (__attribute__((address_space(3))) void*)(Bs + chunk * 512), 16, 0, 0);
        }
        __syncthreads();
        short8 af[4], bf[4];
#pragma unroll
        for (int t = 0; t < 4; ++t) {
            af[t] = *reinterpret_cast<const short8*>(As + (wm * 64 + t * 16 + l16) * 32 + quad * 8);
            bf[t] = *reinterpret_cast<const short8*>(Bs + (wn * 64 + t * 16 + l16) * 32 + quad * 8);
        }
#pragma unroll
        for (int i = 0; i < 4; i++)
#pragma unroll
            for (int j = 0; j < 4; j++)
                acc[i][j] = __builtin_amdgcn_mfma_f32_16x16x32_bf16(af[i], bf[j], acc[i][j], 0, 0, 0);
    }

#pragma unroll
    for (int i = 0; i < 4; i++)
#pragma unroll
        for (int j = 0; j < 4; j++) {
            const int row = m0 + wm * 64 + i * 16 + quad * 4;
            const int col = n0 + wn * 64 + j * 16 + l16;
#pragma unroll
            for (int r = 0; r < 4; r++) {
                float vv = acc[i][j][r];
                if (OUT_BF16)
                    ((unsigned short*)Cv)[(size_t)(row + r) * N + col] = f2bf(vv);
                else
                    ((float*)Cv)[(size_t)(row + r) * N + col] = vv;
            }
        }
}

// ---------------- RoPE + split/reshape ----------------
// Z: [4096 tokens][6144] bf16. Q[B,NH,S,HD] (pre-scaled by log2e/sqrt(128)),
// K[B,NKV,S,HD], Vt[B,NKV,HD,S].
#define QSCALE 0.12748539509360f   // log2(e) / sqrt(128)
__global__ void rope_split(const unsigned short* __restrict__ Z,
                           unsigned short* __restrict__ Q,
                           unsigned short* __restrict__ Kb,
                           unsigned short* __restrict__ Vt) {
    const int PER_TOK = 2048 + 512 + 1024;  // q-pairs + k-pairs + v-elems
    int idx = blockIdx.x * blockDim.x + threadIdx.x;
    if (idx >= BATCH * S_LEN * PER_TOK) return;
    int t = idx / PER_TOK;
    int r = idx - t * PER_TOK;
    int b = t / S_LEN, s = t - b * S_LEN;
    const unsigned short* z = Z + (size_t)t * NE;
    if (r < 2048) {                 // q pair: C section
        int h = r >> 6, j = r & 63;
        float x0 = bf2f(z[2048 + h * 128 + j]);
        float x1 = bf2f(z[2048 + h * 128 + j + 64]);
        float inv = exp2f((float)j * -0.20762050593f);   // 10000^(-j/64)
        float c, sn; sincosf((float)s * inv, &sn, &c);
        size_t base = ((size_t)(b * NH + h) * S_LEN + s) * HD;
        Q[base + j]      = f2bf((x0 * c - x1 * sn) * QSCALE);
        Q[base + j + 64] = f2bf((x1 * c + x0 * sn) * QSCALE);
    } else if (r < 2560) {          // k pair: B section
        int rr = r - 2048; int kh = rr >> 6, j = rr & 63;
        float x0 = bf2f(z[1024 + kh * 128 + j]);
        float x1 = bf2f(z[1024 + kh * 128 + j + 64]);
        float inv = exp2f((float)j * -0.20762050593f);
        float c, sn; sincosf((float)s * inv, &sn, &c);
        size_t base = ((size_t)(b * NKV + kh) * S_LEN + s) * HD;
        Kb[base + j]      = f2bf(x0 * c - x1 * sn);
        Kb[base + j + 64] = f2bf(x1 * c + x0 * sn);
    } else {                        // v elem: x section, transposed store
        int m = r - 2560; int kh = m >> 7, d = m & 127;
        Vt[((size_t)(b * NKV + kh) * HD + d) * S_LEN + s] = z[m];
    }
}

// ---------------- Flash attention v4 (causal, GQA 4:1) ----------------
// Block = 4 waves x 32 q-rows = 128 q. kv tiles of 64.
// K AND V staged in LDS (global_load_lds w16, chunk^(row&7) swizzle) — v3's
// direct-global V regressed (latency-bound, MfmaUtil 21.5->12.9). Q resident.
// S^T orientation (A=K, B=Q): lane holds 4 consecutive kv per q-row ->
// packed b64 P-writes; K/V frags shared across the 2 q-tiles per wave.
// exp2-no-max (Q pre-scaled to log2 domain) — validated rounds 1-3.
__global__ void __launch_bounds__(256)
attn_kernel(const unsigned short* __restrict__ Q,
            const unsigned short* __restrict__ Kb,
            const unsigned short* __restrict__ Vt,
            unsigned short* __restrict__ Ob) {
    __shared__ unsigned short Ks[64 * 128];   // [kv 64][d 128], 16B-chunk swizzle, 16 KB
    __shared__ unsigned short Vs[128 * 64];   // [d 128][kv 64], 16B-chunk swizzle, 16 KB
    __shared__ unsigned short Ps[4][32 * 64]; // per-wave [q 32][kv 64], 8B-slot swizzle, 16 KB
    const int tid  = threadIdx.x;
    const int w    = tid >> 6;
    const int lane = tid & 63;
    const int quad = lane >> 4;
    const int l16  = lane & 15;
    const int blk = blockIdx.x;
    const int qt = 15 - (blk >> 6);      // heavy q-tiles dispatch first
    const int bh = blk & 63;
    const int h = bh & 31, b = bh >> 5;
    const int kvh = h >> 2;
    const int q0blk = qt * 128;
    const int wq0 = q0blk + w * 32;

    const unsigned short* Qbase = Q  + ((size_t)(b * NH  + h)   * S_LEN) * HD;
    const unsigned short* Kbase = Kb + ((size_t)(b * NKV + kvh) * S_LEN) * HD;
    const unsigned short* Vbase = Vt + ((size_t)(b * NKV + kvh) * HD) * S_LEN;

    // Q B-frags: qf[q_t][ks]: n=l16 -> q=wq0+q_t*16+l16 ; k=quad*8+j -> d=ks*32+quad*8+j
    short8 qf[2][4];
#pragma unroll
    for (int q_t = 0; q_t < 2; ++q_t) {
        const unsigned short* qrow = Qbase + (size_t)(wq0 + q_t * 16 + l16) * HD + quad * 8;
#pragma unroll
        for (int ks = 0; ks < 4; ++ks)
            qf[q_t][ks] = *reinterpret_cast<const short8*>(qrow + ks * 32);
    }

    floatx4 oacc[2][8];
#pragma unroll
    for (int q_t = 0; q_t < 2; ++q_t)
#pragma unroll
        for (int dt = 0; dt < 8; ++dt) oacc[q_t][dt] = {0.f, 0.f, 0.f, 0.f};
    float lsum[2] = {0.f, 0.f};

    const int stg_row = lane >> 4;       // K staging: row-in-4 group
    const int stg_pc  = lane & 15;
    const int v_pc    = lane & 7;        // V staging: chunk within row
    unsigned short* pw = &Ps[w][0];
    const int e2 = (l16 & 7) << 1;       // P-buffer XOR swizzle (parity-preserving)
    const int kv_end = q0blk + 128;

    for (int kv0 = 0; kv0 < kv_end; kv0 += 64) {
        __syncthreads();   // previous-iter Ks/Vs reads complete before overwrite
        // ---- stage K tile (64 rows x 256 B): 16 instrs, 4 per wave ----
#pragma unroll
        for (int c = 0; c < 4; ++c) {
            const int bI = w * 4 + c;                   // wave-uniform
            const int row = bI * 4 + stg_row;           // 0..63
            const int lc = stg_pc ^ (row & 7);
            const unsigned short* ga = Kbase + (size_t)(kv0 + row) * HD + lc * 8;
            __builtin_amdgcn_global_load_lds(
                (const __attribute__((address_space(1))) void*)ga,
                (__attribute__((address_space(3))) void*)(Ks + bI * 512), 16, 0, 0);
        }
        // ---- stage V^T tile (128 d-rows x 128 B): 16 instrs, 4 per wave ----
#pragma unroll
        for (int c = 0; c < 4; ++c) {
            const int bI = w * 4 + c;
            const int drow = bI * 8 + (lane >> 3);      // 0..127
            const int lc = v_pc ^ (drow & 7);
            const unsigned short* ga = Vbase + (size_t)drow * S_LEN + kv0 + lc * 8;
            __builtin_amdgcn_global_load_lds(
                (const __attribute__((address_space(1))) void*)ga,
                (__attribute__((address_space(3))) void*)(Vs + bI * 512), 16, 0, 0);
        }
        __syncthreads();   // staging complete

        if (kv0 < wq0 + 32) {            // wave has at least one unmasked column
            const bool diag = (kv0 + 63 > wq0);
            // ---- QK^T (S^T): A=K (m=kv, 4 tiles), B=Q (n=q, 2 tiles), 4 k-chunks ----
            floatx4 sacc[2][4];
#pragma unroll
            for (int q_t = 0; q_t < 2; ++q_t)
#pragma unroll
                for (int mt = 0; mt < 4; ++mt) sacc[q_t][mt] = {0.f, 0.f, 0.f, 0.f};
#pragma unroll
            for (int ks = 0; ks < 4; ++ks) {
#pragma unroll
                for (int mt = 0; mt < 4; ++mt) {
                    const int row = mt * 16 + l16;
                    const int slot = (ks * 4 + quad) ^ (l16 & 7);
                    short8 kf = *reinterpret_cast<const short8*>(Ks + row * 128 + slot * 8);
#pragma unroll
                    for (int q_t = 0; q_t < 2; ++q_t)
                        sacc[q_t][mt] = __builtin_amdgcn_mfma_f32_16x16x32_bf16(
                            kf, qf[q_t][ks], sacc[q_t][mt], 0, 0, 0);
                }
            }
            // ---- exp2 + mask + packed P store ----
#pragma unroll
            for (int q_t = 0; q_t < 2; ++q_t) {
                const int qrow = wq0 + q_t * 16 + l16;
                const int prow = q_t * 16 + l16;
#pragma unroll
                for (int mt = 0; mt < 4; ++mt) {
                    const int kvb = kv0 + mt * 16 + quad * 4;
                    float p0 = exp2f(sacc[q_t][mt][0]);
                    float p1 = exp2f(sacc[q_t][mt][1]);
                    float p2 = exp2f(sacc[q_t][mt][2]);
                    float p3 = exp2f(sacc[q_t][mt][3]);
                    if (diag) {
                        p0 = (kvb + 0 <= qrow) ? p0 : 0.f;
                        p1 = (kvb + 1 <= qrow) ? p1 : 0.f;
                        p2 = (kvb + 2 <= qrow) ? p2 : 0.f;
                        p3 = (kvb + 3 <= qrow) ? p3 : 0.f;
                    }
                    lsum[q_t] += (p0 + p1) + (p2 + p3);
                    const int phys = (mt * 4 + quad) ^ e2;   // 8B slot, parity kept
                    uint2 pk; pk.x = pack_bf2(p0, p1); pk.y = pack_bf2(p2, p3);
                    *reinterpret_cast<uint2*>(pw + prow * 64 + phys * 4) = pk;
                }
            }
            // ---- PV: A=P (LDS, wave-private), B=V (LDS, shared across q_t) ----
#pragma unroll
            for (int kp = 0; kp < 2; ++kp) {
                short8 pf[2];
#pragma unroll
                for (int q_t = 0; q_t < 2; ++q_t) {
                    const int phys = (kp * 8 + quad * 2) ^ e2;
                    pf[q_t] = *reinterpret_cast<const short8*>(
                        pw + (q_t * 16 + l16) * 64 + phys * 4);
                }
#pragma unroll
                for (int dt = 0; dt < 8; ++dt) {
                    const int drow = dt * 16 + l16;
                    const int pcV = (kp * 4 + quad) ^ (l16 & 7);
                    short8 vf = *reinterpret_cast<const short8*>(Vs + drow * 64 + pcV * 8);
#pragma unroll
                    for (int q_t = 0; q_t < 2; ++q_t)
                        oacc[q_t][dt] = __builtin_amdgcn_mfma_f32_16x16x32_bf16(
                            pf[q_t], vf, oacc[q_t][dt], 0, 0, 0);
                }
            }
        }
    }

    // ---- final row-sum reduce + write ----
#pragma unroll
    for (int q_t = 0; q_t < 2; ++q_t) {
        float s = lsum[q_t];
        s += __shfl_xor(s, 16);
        s += __shfl_xor(s, 32);
        float linv = 1.0f / s;           // lane (any quad, l16) holds sum for q=q_t*16+l16
#pragma unroll
        for (int r = 0; r < 4; ++r) {
            const float lr = __shfl(linv, quad * 4 + r);   // sum for q-row quad*4+r
            const int row = wq0 + q_t * 16 + quad * 4 + r;
#pragma unroll
            for (int dt = 0; dt < 8; ++dt) {
                const int d = dt * 16 + l16;
                Ob[((size_t)(b * S_LEN + row)) * 4096 + h * 128 + d] =
                    f2bf(oacc[q_t][dt][r] * lr);
            }
        }
    }
}

extern "C" void kernel_launch(void* const* d_in, const int* in_sizes, int n_in,
                              void* d_out, int out_size, void* d_ws, size_t ws_size,
                              hipStream_t stream) {
    const float* u     = (const float*)d_in[0];
    const float* W_in  = (const float*)d_in[1];
    const float* W_out = (const float*)d_in[2];
    float* out = (float*)d_out;

    char* ws = (char*)d_ws;
    unsigned short* u_bf    = (unsigned short*)(ws);                    //  16,777,216 B
    unsigned short* win_bf  = (unsigned short*)(ws + 16777216);         //  25,165,824 B
    unsigned short* wout_bf = (unsigned short*)(ws + 41943040);         //  16,777,216 B
    unsigned short* Z       = (unsigned short*)(ws + 58720256);         //  50,331,648 B
    unsigned short* Qb      = (unsigned short*)(ws + 109051904);        //  33,554,432 B
    unsigned short* Kv      = (unsigned short*)(ws + 142606336);        //   8,388,608 B
    unsigned short* Vt      = (unsigned short*)(ws + 150994944);        //   8,388,608 B
    unsigned short* Ob      = (unsigned short*)(ws + 159383552);        //  33,554,432 B
    // total: 192,937,984 B

    {   // casts
        int n4 = (2 * 2048 * 2048) / 4;
        cast_f32_bf16<<<(n4 + 255) / 256, 256, 0, stream>>>(u, u_bf, n4);
        n4 = (6144 * 2048) / 4;   // only the used rows [4096,10240) of W_in
        cast_f32_bf16<<<(n4 + 255) / 256, 256, 0, stream>>>(W_in + (size_t)4096 * 2048, win_bf, n4);
        n4 = (2048 * 4096) / 4;
        cast_f32_bf16<<<(n4 + 255) / 256, 256, 0, stream>>>(W_out, wout_bf, n4);
    }
    {   // GEMM1: Z[4096,6144] = u_bf[4096,2048] @ win_bf[6144,2048]^T
        dim3 g(6144 / 128, 4096 / 128);
        gemm_bt<1><<<g, 256, 0, stream>>>(u_bf, win_bf, Z, 4096, 6144, 2048);
    }
    {   // RoPE + split
        int n = BATCH * S_LEN * 3584;
        rope_split<<<(n + 255) / 256, 256, 0, stream>>>(Z, Qb, Kv, Vt);
    }
    // attention: grid = (S/128) * B * NH, heavy q-tiles first
    attn_kernel<<<BATCH * NH * (S_LEN / 128), 256, 0, stream>>>(Qb, Kv, Vt, Ob);
    {   // GEMM2: out[4096,2048] = Ob[4096,4096] @ wout_bf[2048,4096]^T  (fp32 store)
        dim3 g(2048 / 128, 4096 / 128);
        gemm_bt<0><<<g, 256, 0, stream>>>(Ob, wout_bf, out, 4096, 2048, 4096);
    }
}

// Round 5
// 567.786 us; speedup vs baseline: 1.1436x; 1.0853x over previous
//
#include <hip/hip_runtime.h>
#include <stdint.h>

#define S_LEN 2048
#define BATCH 2
#define NH 32
#define NKV 8
#define HD 128
#define NE 6144   // extracted columns of zxbcdt: x(1024) | B(1024) | C(4096)

typedef __attribute__((ext_vector_type(8))) short short8;
typedef __attribute__((ext_vector_type(4))) float floatx4;

__device__ __forceinline__ unsigned short f2bf(float f) {
    union { float f; uint32_t u; } v; v.f = f;
    uint32_t u = v.u;
    u += 0x7FFFu + ((u >> 16) & 1u);   // RTN-even (inputs are finite)
    return (unsigned short)(u >> 16);
}
__device__ __forceinline__ float bf2f(unsigned short h) {
    union { uint32_t u; float f; } v; v.u = ((uint32_t)h) << 16;
    return v.f;
}
__device__ __forceinline__ uint32_t rtn_u(float f) {
    union { float f; uint32_t u; } v; v.f = f;
    return v.u + 0x7FFFu + ((v.u >> 16) & 1u);
}
// pack two fp32 -> {bf16(a) lo, bf16(b) hi} in one v_perm after rounding
__device__ __forceinline__ uint32_t pack_bf2(float a, float b) {
    return __builtin_amdgcn_perm(rtn_u(b), rtn_u(a), 0x07060302);
}

// ---------------- cast fp32 -> bf16, 4 elems/thread ----------------
__global__ void cast_f32_bf16(const float* __restrict__ in,
                              unsigned short* __restrict__ out, int n4) {
    int i = blockIdx.x * blockDim.x + threadIdx.x;
    if (i >= n4) return;
    float4 f = reinterpret_cast<const float4*>(in)[i];
    ushort4 o;
    o.x = f2bf(f.x); o.y = f2bf(f.y); o.z = f2bf(f.z); o.w = f2bf(f.w);
    reinterpret_cast<ushort4*>(out)[i] = o;
}

// ---------------- m97-style B^T GEMM: C[M,N] = A[M,K] * Bt[N,K]^T ----------------
template <int OUT_BF16>
__global__ void __launch_bounds__(256)
gemm_bt(const unsigned short* __restrict__ A, const unsigned short* __restrict__ Bt,
        void* __restrict__ Cv, int M, int N, int K) {
    __shared__ unsigned short As[128 * 32];
    __shared__ unsigned short Bs[128 * 32];
    const int tid  = threadIdx.x;
    const int w    = tid >> 6;
    const int lane = tid & 63;
    const int quad = lane >> 4;
    const int l16  = lane & 15;
    const int wm   = w >> 1, wn = w & 1;
    const int m0 = blockIdx.y * 128, n0 = blockIdx.x * 128;

    floatx4 acc[4][4];
#pragma unroll
    for (int i = 0; i < 4; i++)
#pragma unroll
        for (int j = 0; j < 4; j++) acc[i][j] = {0.f, 0.f, 0.f, 0.f};

    const int lr = lane >> 2;        // row within 16-row chunk
    const int lk = (lane & 3) * 8;   // k-elem offset within 32
    const int KT = K >> 5;

    for (int kt = 0; kt < KT; ++kt) {
        const int k0 = kt << 5;
        __syncthreads();
#pragma unroll
        for (int c = 0; c < 2; ++c) {
            const int chunk = w * 2 + c;  // wave-uniform
            const unsigned short* ga = A  + (size_t)(m0 + chunk * 16 + lr) * K + k0 + lk;
            __builtin_amdgcn_global_load_lds(
                (const __attribute__((address_space(1))) void*)ga,
                (__attribute__((address_space(3))) void*)(As + chunk * 512), 16, 0, 0);
            const unsigned short* gb = Bt + (size_t)(n0 + chunk * 16 + lr) * K + k0 + lk;
            __builtin_amdgcn_global_load_lds(
                (const __attribute__((address_space(1))) void*)gb,
                (__attribute__((address_space(3))) void*)(Bs + chunk * 512), 16, 0, 0);
        }
        __syncthreads();
        short8 af[4], bf[4];
#pragma unroll
        for (int t = 0; t < 4; ++t) {
            af[t] = *reinterpret_cast<const short8*>(As + (wm * 64 + t * 16 + l16) * 32 + quad * 8);
            bf[t] = *reinterpret_cast<const short8*>(Bs + (wn * 64 + t * 16 + l16) * 32 + quad * 8);
        }
#pragma unroll
        for (int i = 0; i < 4; i++)
#pragma unroll
            for (int j = 0; j < 4; j++)
                acc[i][j] = __builtin_amdgcn_mfma_f32_16x16x32_bf16(af[i], bf[j], acc[i][j], 0, 0, 0);
    }

#pragma unroll
    for (int i = 0; i < 4; i++)
#pragma unroll
        for (int j = 0; j < 4; j++) {
            const int row = m0 + wm * 64 + i * 16 + quad * 4;
            const int col = n0 + wn * 64 + j * 16 + l16;
#pragma unroll
            for (int r = 0; r < 4; r++) {
                float vv = acc[i][j][r];
                if (OUT_BF16)
                    ((unsigned short*)Cv)[(size_t)(row + r) * N + col] = f2bf(vv);
                else
                    ((float*)Cv)[(size_t)(row + r) * N + col] = vv;
            }
        }
}

// ---------------- RoPE + split/reshape ----------------
// Z: [4096 tokens][6144] bf16. Q[B,NH,S,HD] (pre-scaled by log2e/sqrt(128)),
// K[B,NKV,S,HD], Vt[B,NKV,HD,S].
#define QSCALE 0.12748539509360f   // log2(e) / sqrt(128)
__global__ void rope_split(const unsigned short* __restrict__ Z,
                           unsigned short* __restrict__ Q,
                           unsigned short* __restrict__ Kb,
                           unsigned short* __restrict__ Vt) {
    const int PER_TOK = 2048 + 512 + 1024;  // q-pairs + k-pairs + v-elems
    int idx = blockIdx.x * blockDim.x + threadIdx.x;
    if (idx >= BATCH * S_LEN * PER_TOK) return;
    int t = idx / PER_TOK;
    int r = idx - t * PER_TOK;
    int b = t / S_LEN, s = t - b * S_LEN;
    const unsigned short* z = Z + (size_t)t * NE;
    if (r < 2048) {                 // q pair: C section
        int h = r >> 6, j = r & 63;
        float x0 = bf2f(z[2048 + h * 128 + j]);
        float x1 = bf2f(z[2048 + h * 128 + j + 64]);
        float inv = exp2f((float)j * -0.20762050593f);   // 10000^(-j/64)
        float c, sn; sincosf((float)s * inv, &sn, &c);
        size_t base = ((size_t)(b * NH + h) * S_LEN + s) * HD;
        Q[base + j]      = f2bf((x0 * c - x1 * sn) * QSCALE);
        Q[base + j + 64] = f2bf((x1 * c + x0 * sn) * QSCALE);
    } else if (r < 2560) {          // k pair: B section
        int rr = r - 2048; int kh = rr >> 6, j = rr & 63;
        float x0 = bf2f(z[1024 + kh * 128 + j]);
        float x1 = bf2f(z[1024 + kh * 128 + j + 64]);
        float inv = exp2f((float)j * -0.20762050593f);
        float c, sn; sincosf((float)s * inv, &sn, &c);
        size_t base = ((size_t)(b * NKV + kh) * S_LEN + s) * HD;
        Kb[base + j]      = f2bf(x0 * c - x1 * sn);
        Kb[base + j + 64] = f2bf(x1 * c + x0 * sn);
    } else {                        // v elem: x section, transposed store
        int m = r - 2560; int kh = m >> 7, d = m & 127;
        Vt[((size_t)(b * NKV + kh) * HD + d) * S_LEN + s] = z[m];
    }
}

// ---------------- Flash attention v5 (causal, GQA 4:1) ----------------
// R2's TLP shape (64q/block, 16q/wave, kv 64, 2048 blocks, 40KB LDS ->
// 4 blocks/CU) + R4's S^T low-VALU machinery. R3/R4 proved occupancy
// dominates DS bytes here; this keeps occupancy and cuts VALU.
// S^T (A=K, B=Q): lane owns ONE q-row (q=l16), 4 consecutive kv per reg ->
// packed b64 P-writes, scalar lsum, single end reduction.
// exp2-no-max (Q pre-scaled to log2 domain) — validated rounds 1-4.
__global__ void __launch_bounds__(256)
attn_kernel(const unsigned short* __restrict__ Q,
            const unsigned short* __restrict__ Kb,
            const unsigned short* __restrict__ Vt,
            unsigned short* __restrict__ Ob) {
    __shared__ unsigned short Ks[64 * 128];   // [kv 64][d 128], 16B-chunk swizzle, 16 KB
    __shared__ unsigned short Vs[128 * 64];   // [d 128][kv 64], 16B-chunk swizzle, 16 KB
    __shared__ unsigned short Ps[4][16 * 64]; // per-wave [q 16][kv 64], 8B-slot swizzle, 8 KB
    const int tid  = threadIdx.x;
    const int w    = tid >> 6;
    const int lane = tid & 63;
    const int quad = lane >> 4;
    const int l16  = lane & 15;
    const int blk = blockIdx.x;
    const int qt = 31 - (blk >> 6);      // heavy q-tiles dispatch first
    const int bh = blk & 63;
    const int h = bh & 31, b = bh >> 5;
    const int kvh = h >> 2;
    const int q0blk = qt * 64;
    const int wq0 = q0blk + w * 16;

    const unsigned short* Qbase = Q  + ((size_t)(b * NH  + h)   * S_LEN) * HD;
    const unsigned short* Kbase = Kb + ((size_t)(b * NKV + kvh) * S_LEN) * HD;
    const unsigned short* Vbase = Vt + ((size_t)(b * NKV + kvh) * HD) * S_LEN;

    // Q B-frags: qf[ks]: n=l16 -> q=wq0+l16 ; k=quad*8+j -> d=ks*32+quad*8+j
    short8 qf[4];
    {
        const unsigned short* qrow = Qbase + (size_t)(wq0 + l16) * HD + quad * 8;
#pragma unroll
        for (int ks = 0; ks < 4; ++ks)
            qf[ks] = *reinterpret_cast<const short8*>(qrow + ks * 32);
    }

    floatx4 oacc[8];
#pragma unroll
    for (int dt = 0; dt < 8; ++dt) oacc[dt] = {0.f, 0.f, 0.f, 0.f};
    float lsum = 0.f;

    const int stg_row = lane >> 4;       // K staging: row-in-4 group
    const int stg_pc  = lane & 15;
    const int v_pc    = lane & 7;        // V staging: chunk within row
    unsigned short* pw = &Ps[w][0];
    const int e2 = (l16 & 7) << 1;       // P-buffer XOR swizzle (parity-preserving)
    const int kv_end = q0blk + 64;

    for (int kv0 = 0; kv0 < kv_end; kv0 += 64) {
        __syncthreads();   // previous-iter Ks/Vs reads complete before overwrite
        // ---- stage K tile (64 rows x 256 B): 16 instrs, 4 per wave ----
#pragma unroll
        for (int c = 0; c < 4; ++c) {
            const int bI = w * 4 + c;                   // wave-uniform
            const int row = bI * 4 + stg_row;           // 0..63
            const int lc = stg_pc ^ (row & 7);
            const unsigned short* ga = Kbase + (size_t)(kv0 + row) * HD + lc * 8;
            __builtin_amdgcn_global_load_lds(
                (const __attribute__((address_space(1))) void*)ga,
                (__attribute__((address_space(3))) void*)(Ks + bI * 512), 16, 0, 0);
        }
        // ---- stage V^T tile (128 d-rows x 128 B): 16 instrs, 4 per wave ----
#pragma unroll
        for (int c = 0; c < 4; ++c) {
            const int bI = w * 4 + c;
            const int drow = bI * 8 + (lane >> 3);      // 0..127
            const int lc = v_pc ^ (drow & 7);
            const unsigned short* ga = Vbase + (size_t)drow * S_LEN + kv0 + lc * 8;
            __builtin_amdgcn_global_load_lds(
                (const __attribute__((address_space(1))) void*)ga,
                (__attribute__((address_space(3))) void*)(Vs + bI * 512), 16, 0, 0);
        }
        __syncthreads();   // staging complete

        if (kv0 < wq0 + 16) {            // wave has at least one unmasked column
            const bool diag = (kv0 + 63 > wq0);
            // ---- QK^T (S^T): A=K (m=kv, 4 tiles), B=Q (n=16q), 4 k-chunks ----
            floatx4 sacc[4];
#pragma unroll
            for (int mt = 0; mt < 4; ++mt) sacc[mt] = {0.f, 0.f, 0.f, 0.f};
#pragma unroll
            for (int ks = 0; ks < 4; ++ks) {
#pragma unroll
                for (int mt = 0; mt < 4; ++mt) {
                    const int row = mt * 16 + l16;
                    const int slot = (ks * 4 + quad) ^ (l16 & 7);
                    short8 kf = *reinterpret_cast<const short8*>(Ks + row * 128 + slot * 8);
                    sacc[mt] = __builtin_amdgcn_mfma_f32_16x16x32_bf16(
                        kf, qf[ks], sacc[mt], 0, 0, 0);
                }
            }
            // ---- exp2 + mask + packed P store (lane owns q-row wq0+l16) ----
            const int qrow = wq0 + l16;
#pragma unroll
            for (int mt = 0; mt < 4; ++mt) {
                const int kvb = kv0 + mt * 16 + quad * 4;
                float p0 = exp2f(sacc[mt][0]);
                float p1 = exp2f(sacc[mt][1]);
                float p2 = exp2f(sacc[mt][2]);
                float p3 = exp2f(sacc[mt][3]);
                if (diag) {
                    p0 = (kvb + 0 <= qrow) ? p0 : 0.f;
                    p1 = (kvb + 1 <= qrow) ? p1 : 0.f;
                    p2 = (kvb + 2 <= qrow) ? p2 : 0.f;
                    p3 = (kvb + 3 <= qrow) ? p3 : 0.f;
                }
                lsum += (p0 + p1) + (p2 + p3);
                const int phys = (mt * 4 + quad) ^ e2;   // 8B slot, parity kept
                uint2 pk; pk.x = pack_bf2(p0, p1); pk.y = pack_bf2(p2, p3);
                *reinterpret_cast<uint2*>(pw + l16 * 64 + phys * 4) = pk;
            }
            // ---- PV: A=P (LDS, wave-private), B=V (LDS) ----
#pragma unroll
            for (int kp = 0; kp < 2; ++kp) {
                const int physP = (kp * 8 + quad * 2) ^ e2;
                short8 pf = *reinterpret_cast<const short8*>(pw + l16 * 64 + physP * 4);
#pragma unroll
                for (int dt = 0; dt < 8; ++dt) {
                    const int drow = dt * 16 + l16;
                    const int pcV = (kp * 4 + quad) ^ (l16 & 7);
                    short8 vf = *reinterpret_cast<const short8*>(Vs + drow * 64 + pcV * 8);
                    oacc[dt] = __builtin_amdgcn_mfma_f32_16x16x32_bf16(
                        pf, vf, oacc[dt], 0, 0, 0);
                }
            }
        }
    }

    // ---- final row-sum reduce + write ----
    float s = lsum;
    s += __shfl_xor(s, 16);
    s += __shfl_xor(s, 32);
    float linv = 1.0f / s;               // lane holds inv-sum for q = wq0 + l16
#pragma unroll
    for (int r = 0; r < 4; ++r) {
        const float lr = __shfl(linv, quad * 4 + r);   // inv-sum for q-row quad*4+r
        const int row = wq0 + quad * 4 + r;
#pragma unroll
        for (int dt = 0; dt < 8; ++dt) {
            const int d = dt * 16 + l16;
            Ob[((size_t)(b * S_LEN + row)) * 4096 + h * 128 + d] =
                f2bf(oacc[dt][r] * lr);
        }
    }
}

extern "C" void kernel_launch(void* const* d_in, const int* in_sizes, int n_in,
                              void* d_out, int out_size, void* d_ws, size_t ws_size,
                              hipStream_t stream) {
    const float* u     = (const float*)d_in[0];
    const float* W_in  = (const float*)d_in[1];
    const float* W_out = (const float*)d_in[2];
    float* out = (float*)d_out;

    char* ws = (char*)d_ws;
    unsigned short* u_bf    = (unsigned short*)(ws);                    //  16,777,216 B
    unsigned short* win_bf  = (unsigned short*)(ws + 16777216);         //  25,165,824 B
    unsigned short* wout_bf = (unsigned short*)(ws + 41943040);         //  16,777,216 B
    unsigned short* Z       = (unsigned short*)(ws + 58720256);         //  50,331,648 B
    unsigned short* Qb      = (unsigned short*)(ws + 109051904);        //  33,554,432 B
    unsigned short* Kv      = (unsigned short*)(ws + 142606336);        //   8,388,608 B
    unsigned short* Vt      = (unsigned short*)(ws + 150994944);        //   8,388,608 B
    unsigned short* Ob      = (unsigned short*)(ws + 159383552);        //  33,554,432 B
    // total: 192,937,984 B

    {   // casts
        int n4 = (2 * 2048 * 2048) / 4;
        cast_f32_bf16<<<(n4 + 255) / 256, 256, 0, stream>>>(u, u_bf, n4);
        n4 = (6144 * 2048) / 4;   // only the used rows [4096,10240) of W_in
        cast_f32_bf16<<<(n4 + 255) / 256, 256, 0, stream>>>(W_in + (size_t)4096 * 2048, win_bf, n4);
        n4 = (2048 * 4096) / 4;
        cast_f32_bf16<<<(n4 + 255) / 256, 256, 0, stream>>>(W_out, wout_bf, n4);
    }
    {   // GEMM1: Z[4096,6144] = u_bf[4096,2048] @ win_bf[6144,2048]^T
        dim3 g(6144 / 128, 4096 / 128);
        gemm_bt<1><<<g, 256, 0, stream>>>(u_bf, win_bf, Z, 4096, 6144, 2048);
    }
    {   // RoPE + split
        int n = BATCH * S_LEN * 3584;
        rope_split<<<(n + 255) / 256, 256, 0, stream>>>(Z, Qb, Kv, Vt);
    }
    // attention: grid = (S/64) * B * NH, heavy q-tiles first
    attn_kernel<<<BATCH * NH * (S_LEN / 64), 256, 0, stream>>>(Qb, Kv, Vt, Ob);
    {   // GEMM2: out[4096,2048] = Ob[4096,4096] @ wout_bf[2048,4096]^T  (fp32 store)
        dim3 g(2048 / 128, 4096 / 128);
        gemm_bt<0><<<g, 256, 0, stream>>>(Ob, wout_bf, out, 4096, 2048, 4096);
    }
}